// Round 4
// baseline (254.293 us; speedup 1.0000x reference)
//
#include <hip/hip_runtime.h>
#include <hip/hip_bf16.h>

// CRF forward: B=512 chains, T=1024, L=48. One wave per chain.
// Scaled-probability scan: e'[m] = (sum_l e[l]*Et[l][m]) * w[m].
// e broadcast via LDS: 1 ds_write + 12 uniform ds_read_b128 (HW broadcast).
// Et = exp(trans[l][m]) in 48 named float scalars, register-resident:
// amdgpu_waves_per_eu(1,1) gives the allocator the full VGPR budget
// (512 waves on 1024 SIMDs -> occupancy 1/EU costs nothing).
// w = 2^(emit*log2e - c), lagged normalizer c = log2(e_prev[0]) via readlane.

constexpr int Bb = 512;
constexpr int Tt = 1024;
constexpr int Ll = 48;
constexpr int PF = 4;   // prefetch depth (steps)

#define LOG2E_F 1.44269504088896340736f
#define LN2_F   0.69314718055994530942f

__device__ __forceinline__ float rl_f(float v, int l) {
    return __uint_as_float(__builtin_amdgcn_readlane(__float_as_uint(v), (unsigned)l));
}
__device__ __forceinline__ float fexp2(float x) {
    return __builtin_amdgcn_exp2f(x);
}
__device__ __forceinline__ float flog2(float x) {
    return __builtin_amdgcn_logf(x);   // v_log_f32 = log2
}

__global__ __launch_bounds__(64)
__attribute__((amdgpu_waves_per_eu(1, 1)))
void crf_fwd_kernel(const float* __restrict__ y_true,
                    const float* __restrict__ y_pred,
                    const float* __restrict__ trans,
                    float* __restrict__ out)
{
    const int b    = blockIdx.x;
    const int lane = threadIdx.x;
    const int ml   = lane < Ll ? lane : (Ll - 1);   // clamped dest-label index
    const bool act = lane < Ll;

    __shared__ float str[Ll * Ll];                  // trans (score gather + Et build)
    __shared__ __align__(16) float ebuf[64];        // e broadcast buffer
    for (int i = lane; i < Ll * Ll; i += 64) str[i] = trans[i];
    __syncthreads();

    // Et[l] = exp(trans[l][ml]) as 48 named scalars — static accesses only.
#define MK_E(l) float E##l = fexp2(str[(l) * Ll + ml] * LOG2E_F);
    MK_E(0)  MK_E(1)  MK_E(2)  MK_E(3)  MK_E(4)  MK_E(5)  MK_E(6)  MK_E(7)
    MK_E(8)  MK_E(9)  MK_E(10) MK_E(11) MK_E(12) MK_E(13) MK_E(14) MK_E(15)
    MK_E(16) MK_E(17) MK_E(18) MK_E(19) MK_E(20) MK_E(21) MK_E(22) MK_E(23)
    MK_E(24) MK_E(25) MK_E(26) MK_E(27) MK_E(28) MK_E(29) MK_E(30) MK_E(31)
    MK_E(32) MK_E(33) MK_E(34) MK_E(35) MK_E(36) MK_E(37) MK_E(38) MK_E(39)
    MK_E(40) MK_E(41) MK_E(42) MK_E(43) MK_E(44) MK_E(45) MK_E(46) MK_E(47)
#undef MK_E

    const float* __restrict__ yprow = y_pred + (size_t)b * Tt * Ll;
    const float* __restrict__ ytrow = y_true + (size_t)b * Tt * Ll;

    // t = 0 init
    float raw0 = yprow[ml];
    float e = fexp2(raw0 * LOG2E_F);    // e_0[m] = 2^(alpha0[m]*log2e), S=0
    float S = 0.f;                      // accumulated log2 normalizers
    float ts = 0.f;

    unsigned long long m0 = __ballot(act && (ytrow[ml] > 0.5f));
    int labPrev = __ffsll(m0) - 1;
    float ps = rl_f(raw0, labPrev);     // point score, t=0 term

    // One scan step. Normalizer via readlane (no DS dependency); e broadcast
    // via 1 ds_write + 12 b128 uniform reads; 48 pure-VGPR fmacs.
#define STEP(raw, ytv)                                                   \
    do {                                                                 \
        ebuf[lane] = e;                                                  \
        float c = flog2(rl_f(e, 0));                                     \
        S += c;                                                          \
        float w = fexp2(fmaf((raw), LOG2E_F, -c));                       \
        unsigned long long bm = __ballot(act && ((ytv) > 0.5f));         \
        int lab = __ffsll(bm) - 1;                                       \
        ps += rl_f((raw), lab);                                          \
        ts += str[labPrev * Ll + lab];                                   \
        labPrev = lab;                                                   \
        float a0 = 0.f, a1 = 0.f, a2 = 0.f, a3 = 0.f;                    \
        { float4 bc = *(const float4*)&ebuf[0];                          \
          a0 = fmaf(bc.x, E0,  a0); a1 = fmaf(bc.y, E1,  a1);            \
          a2 = fmaf(bc.z, E2,  a2); a3 = fmaf(bc.w, E3,  a3); }          \
        { float4 bc = *(const float4*)&ebuf[4];                          \
          a0 = fmaf(bc.x, E4,  a0); a1 = fmaf(bc.y, E5,  a1);            \
          a2 = fmaf(bc.z, E6,  a2); a3 = fmaf(bc.w, E7,  a3); }          \
        { float4 bc = *(const float4*)&ebuf[8];                          \
          a0 = fmaf(bc.x, E8,  a0); a1 = fmaf(bc.y, E9,  a1);            \
          a2 = fmaf(bc.z, E10, a2); a3 = fmaf(bc.w, E11, a3); }          \
        { float4 bc = *(const float4*)&ebuf[12];                         \
          a0 = fmaf(bc.x, E12, a0); a1 = fmaf(bc.y, E13, a1);            \
          a2 = fmaf(bc.z, E14, a2); a3 = fmaf(bc.w, E15, a3); }          \
        { float4 bc = *(const float4*)&ebuf[16];                         \
          a0 = fmaf(bc.x, E16, a0); a1 = fmaf(bc.y, E17, a1);            \
          a2 = fmaf(bc.z, E18, a2); a3 = fmaf(bc.w, E19, a3); }          \
        { float4 bc = *(const float4*)&ebuf[20];                         \
          a0 = fmaf(bc.x, E20, a0); a1 = fmaf(bc.y, E21, a1);            \
          a2 = fmaf(bc.z, E22, a2); a3 = fmaf(bc.w, E23, a3); }          \
        { float4 bc = *(const float4*)&ebuf[24];                         \
          a0 = fmaf(bc.x, E24, a0); a1 = fmaf(bc.y, E25, a1);            \
          a2 = fmaf(bc.z, E26, a2); a3 = fmaf(bc.w, E27, a3); }          \
        { float4 bc = *(const float4*)&ebuf[28];                         \
          a0 = fmaf(bc.x, E28, a0); a1 = fmaf(bc.y, E29, a1);            \
          a2 = fmaf(bc.z, E30, a2); a3 = fmaf(bc.w, E31, a3); }          \
        { float4 bc = *(const float4*)&ebuf[32];                         \
          a0 = fmaf(bc.x, E32, a0); a1 = fmaf(bc.y, E33, a1);            \
          a2 = fmaf(bc.z, E34, a2); a3 = fmaf(bc.w, E35, a3); }          \
        { float4 bc = *(const float4*)&ebuf[36];                         \
          a0 = fmaf(bc.x, E36, a0); a1 = fmaf(bc.y, E37, a1);            \
          a2 = fmaf(bc.z, E38, a2); a3 = fmaf(bc.w, E39, a3); }          \
        { float4 bc = *(const float4*)&ebuf[40];                         \
          a0 = fmaf(bc.x, E40, a0); a1 = fmaf(bc.y, E41, a1);            \
          a2 = fmaf(bc.z, E42, a2); a3 = fmaf(bc.w, E43, a3); }          \
        { float4 bc = *(const float4*)&ebuf[44];                         \
          a0 = fmaf(bc.x, E44, a0); a1 = fmaf(bc.y, E45, a1);            \
          a2 = fmaf(bc.z, E46, a2); a3 = fmaf(bc.w, E47, a3); }          \
        e = ((a0 + a1) + (a2 + a3)) * w;                                 \
    } while (0)

    // prefetch pipeline: pfP/pfT hold rows t0..t0+PF-1
    float pfP[PF], pfT[PF];
    #pragma unroll
    for (int j = 0; j < PF; ++j) {
        pfP[j] = yprow[(1 + j) * Ll + ml];
        pfT[j] = ytrow[(1 + j) * Ll + ml];
    }

    // main: steps t = 1..1020 in chunks of PF
    for (int t0 = 1; t0 <= Tt - PF - 3; t0 += PF) {
        #pragma unroll
        for (int j = 0; j < PF; ++j) {
            float raw = pfP[j];
            float ytv = pfT[j];
            int tn = t0 + j + PF;
            tn = tn < Tt ? tn : (Tt - 1);           // clamp (harmless reload)
            pfP[j] = yprow[tn * Ll + ml];
            pfT[j] = ytrow[tn * Ll + ml];
            STEP(raw, ytv);
        }
    }
    // tail: t = 1021, 1022, 1023
    STEP(pfP[0], pfT[0]);
    STEP(pfP[1], pfT[1]);
    STEP(pfP[2], pfT[2]);
#undef STEP

    // epilogue: log_norm = ln2 * (S + log2(sum_m e[m]))
    float es = act ? e : 0.f;
    #pragma unroll
    for (int off = 32; off >= 1; off >>= 1) es += __shfl_xor(es, off);

    if (lane == 0) {
        float log_norm = LN2_F * (S + flog2(es));
        out[b] = log_norm - ps - ts;
    }
}

extern "C" void kernel_launch(void* const* d_in, const int* in_sizes, int n_in,
                              void* d_out, int out_size, void* d_ws, size_t ws_size,
                              hipStream_t stream) {
    const float* y_true = (const float*)d_in[0];
    const float* y_pred = (const float*)d_in[1];
    const float* trans  = (const float*)d_in[2];
    float* out = (float*)d_out;

    crf_fwd_kernel<<<Bb, 64, 0, stream>>>(y_true, y_pred, trans, out);
}